// Round 5
// baseline (151.356 us; speedup 1.0000x reference)
//
#include <hip/hip_runtime.h>
#include <cstdint>
#include <cstddef>

#define NB 8192        // buckets: loss>=0 so bits>>18 = 0+exp(8)+5 mantissa bits
#define TH 1024
#define GRID 512       // 2 blocks/CU * 256 CU

__device__ __forceinline__ float bce_loss(float x, float t) {
  // stable BCE-with-logits, fast transcendentals (err ~1e-6 << 2.5e-2 threshold)
  float u = __expf(-fabsf(x));
  return fmaxf(x, 0.0f) - x * t + __logf(1.0f + u);
}

__device__ __forceinline__ float bucket_mid(unsigned int b) {
  // arithmetic midpoint of bucket [b<<18, (b+1)<<18).
  // NOTE: for b >= 8160 this bit pattern is Inf/NaN — callers must only use it
  // for buckets with nonzero count (real losses are finite, <~6).
  return __uint_as_float((b << 18) | 0x20000u);
}

// ---------------- single pass: count-only histogram on bits>>18 ----------
// Latency fix vs R4: 4 independent float4 pairs in flight per iteration
// (VGPR=12 -> ~40; one vmcnt wait covers 16 elements of compute).
__global__ __launch_bounds__(TH) void hist_kernel(
    const float* __restrict__ pred, const float* __restrict__ targ,
    unsigned int N, unsigned int* __restrict__ hist) {
  __shared__ unsigned int h[2][NB];  // 2 replicas: halves same-address pressure
  int tid = threadIdx.x;
  for (int i = tid; i < 2 * NB; i += TH) ((unsigned int*)h)[i] = 0u;
  __syncthreads();
  unsigned int* hh = h[(tid >> 6) & 1];
  unsigned int n4 = N >> 2;
  const float4* p4 = (const float4*)pred;
  const float4* t4 = (const float4*)targ;
  unsigned int stride = gridDim.x * blockDim.x;
  unsigned int i = blockIdx.x * blockDim.x + tid;
  // unroll x4: loads at i + k*stride stay per-instruction coalesced
  for (; i + 3 * stride < n4; i += 4 * stride) {
    float4 xs0 = p4[i];
    float4 xs1 = p4[i + stride];
    float4 xs2 = p4[i + 2 * stride];
    float4 xs3 = p4[i + 3 * stride];
    float4 ts0 = t4[i];
    float4 ts1 = t4[i + stride];
    float4 ts2 = t4[i + 2 * stride];
    float4 ts3 = t4[i + 3 * stride];
    float l;
#define H1(xx, tt)                                                        \
    l = fmaxf(bce_loss(xx, tt), 0.0f);                                    \
    atomicAdd(&hh[__float_as_uint(l) >> 18], 1u);
#define H4(k)                                                             \
    H1(xs##k.x, ts##k.x) H1(xs##k.y, ts##k.y)                             \
    H1(xs##k.z, ts##k.z) H1(xs##k.w, ts##k.w)
    H4(0) H4(1) H4(2) H4(3)
#undef H4
  }
  for (; i < n4; i += stride) {  // remainder float4 groups
    float4 x = p4[i];
    float4 t = t4[i];
    float l;
    H1(x.x, t.x) H1(x.y, t.y) H1(x.z, t.z) H1(x.w, t.w)
  }
#undef H1
  if (blockIdx.x == 0) {  // tail (N % 4)
    for (unsigned int j = (n4 << 2) + tid; j < N; j += TH) {
      float l = fmaxf(bce_loss(pred[j], targ[j]), 0.0f);
      atomicAdd(&hh[__float_as_uint(l) >> 18], 1u);
    }
  }
  __syncthreads();
  // ~400 nonzero buckets/block -> cheap global flush
  for (int k = tid; k < NB; k += TH) {
    unsigned int v = h[0][k] + h[1][k];
    if (v) atomicAdd(&hist[k], v);
  }
}

// ---------------- scan: suffix sums, find threshold, emit mean -----------
__global__ __launch_bounds__(512) void scan_kernel(
    const unsigned int* __restrict__ hist, unsigned long long K,
    float* __restrict__ out) {
  __shared__ unsigned long long cs[512];
  __shared__ double ss[512];
  int tid = threadIdx.x;  // 512 threads * 16 buckets = 8192
  unsigned int c[16];
  unsigned long long cnt = 0;
  double wsum = 0.0;
#pragma unroll
  for (int j = 0; j < 16; j++) {
    c[j] = hist[16 * tid + j];
    cnt += c[j];
    // guard: bucket_mid of empty high buckets is Inf/NaN; 0*NaN would poison
    if (c[j]) wsum += (double)c[j] * (double)bucket_mid(16 * tid + j);
  }
  cs[tid] = cnt;
  ss[tid] = wsum;
  __syncthreads();
  // inclusive suffix sum over threads
  for (int off = 1; off < 512; off <<= 1) {
    unsigned long long t = (tid + off < 512) ? cs[tid + off] : 0ULL;
    double td = (tid + off < 512) ? ss[tid + off] : 0.0;
    __syncthreads();
    cs[tid] += t;
    ss[tid] += td;
    __syncthreads();
  }
  unsigned long long ab = (tid < 511) ? cs[tid + 1] : 0ULL;   // strictly above my range
  double wab = (tid < 511) ? ss[tid + 1] : 0.0;
  for (int j = 15; j >= 0; j--) {
    unsigned long long ge = ab + c[j];
    if (ab < K && ge >= K) {  // exactly one (tid,j) satisfies; c[j] >= 1 here
      unsigned long long rem = K - ab;
      double total = wab + (double)rem * (double)bucket_mid(16 * tid + j);
      *out = (float)(total / (double)K);
    }
    ab = ge;
    if (c[j]) wab += (double)c[j] * (double)bucket_mid(16 * tid + j);
  }
}

extern "C" void kernel_launch(void* const* d_in, const int* in_sizes, int n_in,
                              void* d_out, int out_size, void* d_ws,
                              size_t ws_size, hipStream_t stream) {
  const float* pred = (const float*)d_in[0];
  const float* targ = (const float*)d_in[1];
  unsigned int N = (unsigned int)in_sizes[0];
  unsigned long long K = (unsigned long long)(0.25 * (double)N);
  if (K < 1) K = 1;

  unsigned int* hist = (unsigned int*)d_ws;  // 32 KB
  float* out = (float*)d_out;

  // d_ws is re-poisoned to 0xAA before every call; zero via async memset
  // (graph-capturable, cheaper than a dispatch)
  hipMemsetAsync(hist, 0, (size_t)NB * sizeof(unsigned int), stream);
  hist_kernel<<<GRID, TH, 0, stream>>>(pred, targ, N, hist);
  scan_kernel<<<1, 512, 0, stream>>>(hist, K, out);
}